// Round 4
// baseline (138.545 us; speedup 1.0000x reference)
//
#include <hip/hip_runtime.h>

// PatchChamferDistance: B=32, G=64, P=256, D=3 -> BG=2048 patches.
// dist2[i][j] = ||p_i||^2 + ||t_j||^2 - 2 p_i.t_j (clamped >= 0)
// out = mean over patches of (mean_i min_j + mean_j min_i)
//
// Round 4 findings applied:
//  - v_pk_fma_f32 gives NO throughput gain on CDNA4 (round-3 neutral; fp32
//    spec 157.3 TF has no packed factor) -> scalar fma + v_min3_f32
//    (fminf(m, fminf(da,db))): 3.5 slots/dist vs 4.
//  - broadcast ds_read_b128 is cheap (round-3 DS cut was neutral) -> add a
//    4th LDS plane with precomputed ||t||^2, killing per-j norm recompute.
//  - fuse final reduction into the main kernel (atomic + last-block-writes),
//    removing the 2nd launch; 8B memset node zeroes acc/counter.

#define NPATCH 2048
#define NPTS   256

typedef float v4f __attribute__((ext_vector_type(4)));

__global__ __launch_bounds__(256, 4) void chamfer_kernel(
    const float* __restrict__ pred,
    const float* __restrict__ tgt,
    float* __restrict__ ws,      // [0]=float acc, [1]=uint counter (memset 0)
    float* __restrict__ out)
{
    __shared__ float sP[4][NPTS];    // pred planes x,y,z,norm
    __shared__ float sT[4][NPTS];    // tgt  planes x,y,z,norm
    __shared__ float mhalf[2][NPTS]; // per-dir partial mins from half==1 waves
    __shared__ float red[2];

    const int patch = blockIdx.x;
    const int tid   = threadIdx.x;

    // Stage both point sets into SoA LDS planes + norm plane.
    {
        const float* __restrict__ pb = pred + (size_t)patch * (NPTS * 3);
        const float* __restrict__ tb = tgt  + (size_t)patch * (NPTS * 3);
        float x = pb[3 * tid + 0], y = pb[3 * tid + 1], z = pb[3 * tid + 2];
        sP[0][tid] = x; sP[1][tid] = y; sP[2][tid] = z;
        sP[3][tid] = fmaf(z, z, fmaf(y, y, x * x));
        x = tb[3 * tid + 0]; y = tb[3 * tid + 1]; z = tb[3 * tid + 2];
        sT[0][tid] = x; sT[1][tid] = y; sT[2][tid] = z;
        sT[3][tid] = fmaf(z, z, fmaf(y, y, x * x));
    }
    __syncthreads();

    const int wave = tid >> 6;     // 0,1: forward  2,3: backward
    const int lane = tid & 63;
    const int dir  = wave >> 1;    // 0: queries=pred stream=tgt; 1: swapped
    const int half = wave & 1;     // which 128-long j half this wave streams

    const float (*Q)[NPTS] = (dir == 0) ? sP : sT;
    const float (*S)[NPTS] = (dir == 0) ? sT : sP;

    // 4 query points per lane: (-2x,-2y,-2z), norm on the side.
    float qx[4], qy[4], qz[4], qn[4], m[4];
#pragma unroll
    for (int q = 0; q < 4; ++q) {
        const int p = lane + 64 * q;
        qx[q] = -2.0f * Q[0][p];
        qy[q] = -2.0f * Q[1][p];
        qz[q] = -2.0f * Q[2][p];
        qn[q] = Q[3][p];
        m[q]  = 1e30f;
    }

    const int jbase = half * (NPTS / 2);
    const float* __restrict__ Sx = &S[0][jbase];
    const float* __restrict__ Sy = &S[1][jbase];
    const float* __restrict__ Sz = &S[2][jbase];
    const float* __restrict__ Sn = &S[3][jbase];

#pragma unroll 8
    for (int jj = 0; jj < NPTS / 2; jj += 4) {
        const v4f x4 = *(const v4f*)(Sx + jj);
        const v4f y4 = *(const v4f*)(Sy + jj);
        const v4f z4 = *(const v4f*)(Sz + jj);
        const v4f n4 = *(const v4f*)(Sn + jj);
#pragma unroll
        for (int q = 0; q < 4; ++q) {
            const float da = fmaf(qx[q], x4.x, fmaf(qy[q], y4.x, fmaf(qz[q], z4.x, n4.x)));
            const float db = fmaf(qx[q], x4.y, fmaf(qy[q], y4.y, fmaf(qz[q], z4.y, n4.y)));
            m[q] = fminf(m[q], fminf(da, db));   // v_min3_f32
            const float dc = fmaf(qx[q], x4.z, fmaf(qy[q], y4.z, fmaf(qz[q], z4.z, n4.z)));
            const float dd = fmaf(qx[q], x4.w, fmaf(qy[q], y4.w, fmaf(qz[q], z4.w, n4.w)));
            m[q] = fminf(m[q], fminf(dc, dd));   // v_min3_f32
        }
    }

    // Upper-half waves publish per-query mins; lower-half waves combine.
    if (half == 1) {
#pragma unroll
        for (int q = 0; q < 4; ++q)
            mhalf[dir][lane + 64 * q] = m[q];
    }
    __syncthreads();

    if (half == 0) {
        float s = 0.0f;
#pragma unroll
        for (int q = 0; q < 4; ++q) {
            const float mm = fminf(m[q], mhalf[dir][lane + 64 * q]);
            s += fmaxf(qn[q] + mm, 0.0f);
        }
#pragma unroll
        for (int off = 32; off > 0; off >>= 1)
            s += __shfl_down(s, off, 64);
        if (lane == 0) red[dir] = s;
    }
    __syncthreads();

    // Fused finish: accumulate block sums; last-arriving block writes out.
    if (tid == 0) {
        const float bsum = red[0] + red[1];
        __hip_atomic_fetch_add(&ws[0], bsum, __ATOMIC_RELAXED,
                               __HIP_MEMORY_SCOPE_AGENT);
        __threadfence();
        unsigned int* cnt = (unsigned int*)(ws + 1);
        const unsigned int prev = __hip_atomic_fetch_add(
            cnt, 1u, __ATOMIC_ACQ_REL, __HIP_MEMORY_SCOPE_AGENT);
        if (prev == NPATCH - 1) {
            const float total = __hip_atomic_load(&ws[0], __ATOMIC_ACQUIRE,
                                                  __HIP_MEMORY_SCOPE_AGENT);
            out[0] = total * (1.0f / ((float)NPTS * (float)NPATCH));
        }
    }
}

extern "C" void kernel_launch(void* const* d_in, const int* in_sizes, int n_in,
                              void* d_out, int out_size, void* d_ws, size_t ws_size,
                              hipStream_t stream) {
    const float* pred = (const float*)d_in[0];
    const float* tgt  = (const float*)d_in[1];
    float* ws         = (float*)d_ws;
    float* out        = (float*)d_out;

    hipMemsetAsync(ws, 0, 8, stream);  // acc + counter
    chamfer_kernel<<<NPATCH, 256, 0, stream>>>(pred, tgt, ws, out);
}

// Round 5
// 84.184 us; speedup vs baseline: 1.6457x; 1.6457x over previous
//
#include <hip/hip_runtime.h>

// PatchChamferDistance: B=32, G=64, P=256, D=3 -> BG=2048 patches.
// dist2[i][j] = ||p_i||^2 + ||t_j||^2 - 2 p_i.t_j (clamped >= 0)
// out = mean over patches of (mean_i min_j + mean_j min_i)
//
// Round 5: revert round-4's fused atomic finish (agent-scope acq_rel RMW +
// __threadfence per block caused a serialized L2 writeback storm on the
// non-coherent per-XCD L2s: kernel 15 -> 90 us). Back to the round-3
// two-kernel skeleton, keeping the two VALU-slot savers:
//  - scalar fma chain + fminf(m, fminf(da,db)) -> v_min3_f32 (3.5 slots/dist)
//  - 4th LDS plane with precomputed ||t||^2 (no per-j norm recompute;
//    round 3 showed broadcast ds_read_b128 has headroom)
// Known-good facts: v_pk_fma_f32 is NOT dual-rate on CDNA4 (round 3 neutral);
// scalar-pipe streaming regressed (round 2); LDS broadcast is the right feed.

#define NPATCH 2048
#define NPTS   256

typedef float v4f __attribute__((ext_vector_type(4)));

__global__ __launch_bounds__(256, 4) void chamfer_patch_kernel(
    const float* __restrict__ pred,
    const float* __restrict__ tgt,
    float* __restrict__ partial)
{
    __shared__ float sP[4][NPTS];    // pred planes x,y,z,norm
    __shared__ float sT[4][NPTS];    // tgt  planes x,y,z,norm
    __shared__ float mhalf[2][NPTS]; // per-dir partial mins from half==1 waves
    __shared__ float red[2];

    const int patch = blockIdx.x;
    const int tid   = threadIdx.x;

    // Stage both point sets into SoA LDS planes + norm plane.
    {
        const float* __restrict__ pb = pred + (size_t)patch * (NPTS * 3);
        const float* __restrict__ tb = tgt  + (size_t)patch * (NPTS * 3);
        float x = pb[3 * tid + 0], y = pb[3 * tid + 1], z = pb[3 * tid + 2];
        sP[0][tid] = x; sP[1][tid] = y; sP[2][tid] = z;
        sP[3][tid] = fmaf(z, z, fmaf(y, y, x * x));
        x = tb[3 * tid + 0]; y = tb[3 * tid + 1]; z = tb[3 * tid + 2];
        sT[0][tid] = x; sT[1][tid] = y; sT[2][tid] = z;
        sT[3][tid] = fmaf(z, z, fmaf(y, y, x * x));
    }
    __syncthreads();

    const int wave = tid >> 6;     // 0,1: forward  2,3: backward
    const int lane = tid & 63;
    const int dir  = wave >> 1;    // 0: queries=pred stream=tgt; 1: swapped
    const int half = wave & 1;     // which 128-long j half this wave streams

    const float (*Q)[NPTS] = (dir == 0) ? sP : sT;
    const float (*S)[NPTS] = (dir == 0) ? sT : sP;

    // 4 query points per lane: (-2x,-2y,-2z), norm on the side.
    float qx[4], qy[4], qz[4], qn[4], m[4];
#pragma unroll
    for (int q = 0; q < 4; ++q) {
        const int p = lane + 64 * q;
        qx[q] = -2.0f * Q[0][p];
        qy[q] = -2.0f * Q[1][p];
        qz[q] = -2.0f * Q[2][p];
        qn[q] = Q[3][p];
        m[q]  = 1e30f;
    }

    const int jbase = half * (NPTS / 2);
    const float* __restrict__ Sx = &S[0][jbase];
    const float* __restrict__ Sy = &S[1][jbase];
    const float* __restrict__ Sz = &S[2][jbase];
    const float* __restrict__ Sn = &S[3][jbase];

#pragma unroll 4
    for (int jj = 0; jj < NPTS / 2; jj += 4) {
        const v4f x4 = *(const v4f*)(Sx + jj);
        const v4f y4 = *(const v4f*)(Sy + jj);
        const v4f z4 = *(const v4f*)(Sz + jj);
        const v4f n4 = *(const v4f*)(Sn + jj);
#pragma unroll
        for (int q = 0; q < 4; ++q) {
            const float da = fmaf(qx[q], x4.x, fmaf(qy[q], y4.x, fmaf(qz[q], z4.x, n4.x)));
            const float db = fmaf(qx[q], x4.y, fmaf(qy[q], y4.y, fmaf(qz[q], z4.y, n4.y)));
            m[q] = fminf(m[q], fminf(da, db));   // v_min3_f32
            const float dc = fmaf(qx[q], x4.z, fmaf(qy[q], y4.z, fmaf(qz[q], z4.z, n4.z)));
            const float dd = fmaf(qx[q], x4.w, fmaf(qy[q], y4.w, fmaf(qz[q], z4.w, n4.w)));
            m[q] = fminf(m[q], fminf(dc, dd));   // v_min3_f32
        }
    }

    // Upper-half waves publish per-query mins; lower-half waves combine.
    if (half == 1) {
#pragma unroll
        for (int q = 0; q < 4; ++q)
            mhalf[dir][lane + 64 * q] = m[q];
    }
    __syncthreads();

    if (half == 0) {
        float s = 0.0f;
#pragma unroll
        for (int q = 0; q < 4; ++q) {
            const float mm = fminf(m[q], mhalf[dir][lane + 64 * q]);
            s += fmaxf(qn[q] + mm, 0.0f);
        }
#pragma unroll
        for (int off = 32; off > 0; off >>= 1)
            s += __shfl_down(s, off, 64);
        if (lane == 0) red[dir] = s;
    }
    __syncthreads();
    if (tid == 0) partial[patch] = red[0] + red[1];
}

__global__ __launch_bounds__(256) void chamfer_reduce_kernel(
    const float* __restrict__ partial,
    float* __restrict__ out)
{
    __shared__ float red[4];
    const int tid = threadIdx.x;
    float s = 0.0f;
#pragma unroll
    for (int i = tid; i < NPATCH; i += 256) s += partial[i];
#pragma unroll
    for (int off = 32; off > 0; off >>= 1)
        s += __shfl_down(s, off, 64);
    if ((tid & 63) == 0) red[tid >> 6] = s;
    __syncthreads();
    if (tid == 0)
        out[0] = (red[0] + red[1] + red[2] + red[3]) *
                 (1.0f / ((float)NPTS * (float)NPATCH));
}

extern "C" void kernel_launch(void* const* d_in, const int* in_sizes, int n_in,
                              void* d_out, int out_size, void* d_ws, size_t ws_size,
                              hipStream_t stream) {
    const float* pred = (const float*)d_in[0];
    const float* tgt  = (const float*)d_in[1];
    float* partial    = (float*)d_ws;      // 2048 floats = 8 KB scratch
    float* out        = (float*)d_out;

    chamfer_patch_kernel<<<NPATCH, 256, 0, stream>>>(pred, tgt, partial);
    chamfer_reduce_kernel<<<1, 256, 0, stream>>>(partial, out);
}